// Round 2
// baseline (9626.936 us; speedup 1.0000x reference)
//
#include <hip/hip_runtime.h>
#include <cstdint>
#include <cstddef>

// Problem constants (match reference)
#define NIT    500
#define GAMMA_ 5.0f
#define CC_    1e-3f
#define KAPPA_ 2.0627128075074256f
#define PEN_   100.0f
#define LR_    0.01f

// ws layout: pbuf[128 b][3 boundary][2 side][2 parity][100] f32 = 614400 B, then flags[128*3*2] int
#define PBUF_FLOATS (128*3*2*2*100)
#define PBUF_BYTES  (PBUF_FLOATS*4)
#define FLAG_COUNT  (128*3*2)

__device__ __forceinline__ float wred64(float x) {
#pragma unroll
  for (int m = 1; m < 64; m <<= 1) x += __shfl_xor(x, m, 64);
  return x;
}
__device__ __forceinline__ float rdlane(float v, int lane) {
  return __int_as_float(__builtin_amdgcn_readlane(__float_as_int(v), lane));
}

// Grid: 512 WGs = (b, quarter q). WG: 3 heads x 4 waves. Lane owns half-row of S:
//   wave sub: cH = sub>>1 (column half, wave-uniform), rh = sub&1, row r = rh*64+lane (r<100).
//   S[50] per lane = S[r][cH*50 .. cH*50+49], fp32, in VGPRs (launch_bounds caps at ~85 VGPR
//   so 2 WGs/CU stay resident -> all 512 WGs co-resident for the cross-WG head chain).
__global__ __launch_bounds__(768, 6) void mpo_solver(
    const float* __restrict__ mu, const float* __restrict__ L,
    const float* __restrict__ wprev, const float* __restrict__ climit,
    float* __restrict__ out, float* __restrict__ pbuf, int* __restrict__ flags)
{
  const int tid   = threadIdx.x;
  const int lane  = tid & 63;
  const int waveu = __builtin_amdgcn_readfirstlane(tid >> 6);  // 0..11, uniform
  const int j     = waveu >> 2;        // local head 0..2
  const int sub   = waveu & 3;
  const int cHu   = sub >> 1;          // column half, wave-uniform
  const int rh    = sub & 1;
  const int bid   = blockIdx.x;
  const int b     = bid >> 2;
  const int q     = bid & 3;           // quarter: heads q*3 .. q*3+2
  const int h     = q * 3 + j;
  const int bh    = b * 12 + h;

  const int  r      = rh * 64 + lane;
  const bool rvalid = (r < 100);
  const bool val1   = (lane < 36);

  __shared__ float wbuf[2][3][100];    // double-buffered iterate per head
  __shared__ float pm[3][2][100];      // matvec partials [head][colhalf][row]

  const float* Lb = L + (size_t)bh * 10000;

  // ---------- Phase 0: SYRK. S[r][cH*50+cp] = sum_m L[r][m] * L[cH*50+cp][m] ----------
  float S[50];
#pragma unroll
  for (int c = 0; c < 50; ++c) S[c] = 0.f;
  if (rvalid) {
#pragma unroll 1
    for (int mc = 0; mc < 25; ++mc) {
      float4 lr = *(const float4*)(Lb + (size_t)r * 100 + mc * 4);
      const float* Lcb = Lb + cHu * 5000 + mc * 4;   // wave-uniform -> scalar loads
#pragma unroll
      for (int cp = 0; cp < 50; ++cp) {
        const float* Lc = Lcb + cp * 100;
        S[cp] = fmaf(lr.x, Lc[0], fmaf(lr.y, Lc[1], fmaf(lr.z, Lc[2], fmaf(lr.w, Lc[3], S[cp]))));
      }
    }
  }

  // per-lane constants (post wave uses them; harmless elsewhere)
  float mu0 = mu[(size_t)bh * 100 + lane];
  float mu1 = val1 ? mu[(size_t)bh * 100 + 64 + lane] : 0.f;
  float wp0 = wprev[b * 100 + lane];
  float wp1 = val1 ? wprev[b * 100 + 64 + lane] : 0.f;
  float lim = climit[b];

  float w0 = wp0, w1 = wp1;            // post wave's iterate (n = lane, 64+lane)

  if (sub == 0) {
    wbuf[0][j][lane] = wp0;
    if (val1) wbuf[0][j][64 + lane] = wp1;
  }
  __syncthreads();

  const bool hasNext = (h < 11);
  const bool pubR = (j == 2 && q < 3);           // publish right edge -> boundary q, side 0
  const bool pubL = (j == 0 && q > 0);           // publish left edge  -> boundary q-1, side 1
  const int  pubIdx = pubR ? ((b * 3 + q) * 2 + 0) : ((b * 3 + q - 1) * 2 + 1);
  const int  conLIdx = (b * 3 + (q - 1)) * 2 + 0; // consumed by j==0 (q>0)
  const int  conRIdx = (b * 3 + q) * 2 + 1;       // consumed by j==2 (q<3)
  bool dead = false;

  for (int k = 0; k < NIT; ++k) {
    const int p = k & 1;

    // ---------- matvec partial: pm[j][cH][r] = sum_{cp} S[cp] * w[cH*50+cp] ----------
    float vw = (lane < 50) ? wbuf[p][j][cHu * 50 + lane] : 0.f;
    float a0 = 0.f, a1 = 0.f, a2 = 0.f, a3 = 0.f;
#pragma unroll
    for (int c = 0; c < 48; c += 4) {
      a0 = fmaf(rdlane(vw, c + 0), S[c + 0], a0);
      a1 = fmaf(rdlane(vw, c + 1), S[c + 1], a1);
      a2 = fmaf(rdlane(vw, c + 2), S[c + 2], a2);
      a3 = fmaf(rdlane(vw, c + 3), S[c + 3], a3);
    }
    a0 = fmaf(rdlane(vw, 48), S[48], a0);
    a1 = fmaf(rdlane(vw, 49), S[49], a1);
    if (rvalid) pm[j][cHu][r] = (a0 + a2) + (a1 + a3);
    __syncthreads();

    // ---------- post phase: one wave per head (sub==0) ----------
    if (sub == 0) {
      float y0 = pm[j][0][lane] + pm[j][1][lane];
      float y1 = val1 ? (pm[j][0][64 + lane] + pm[j][1][64 + lane]) : 0.f;

      float ret = wred64(fmaf(mu0, w0, mu1 * w1));
      float s2  = wred64(fmaf(y0, w0, y1 * w1));
      float sigma = sqrtf(s2 + 1e-12f);
      float z     = KAPPA_ * sigma - ret - lim;
      float act   = (z > 0.f) ? 1.f : 0.f;
      float cY    = 2.f * GAMMA_ + act * (PEN_ * KAPPA_ / sigma);
      float cM    = -(1.f + act * PEN_);

      // neighbor iterates (lagged, Jacobi — matches reference's simultaneous update)
      float wl0, wl1, wn0 = 0.f, wn1 = 0.f;
      if (j == 0) {
        if (q == 0 || k == 0) { wl0 = wp0; wl1 = wp1; }
        else {
          if (!dead) {
            long guard = 0;
            while (__hip_atomic_load(&flags[conLIdx], __ATOMIC_ACQUIRE, __HIP_MEMORY_SCOPE_AGENT) < k) {
              __builtin_amdgcn_s_sleep(8);
              if (++guard > (1L << 20)) { dead = true; break; }
            }
          }
          const float* src = pbuf + ((size_t)conLIdx * 2 + (k & 1)) * 100;
          wl0 = __hip_atomic_load(&src[lane], __ATOMIC_RELAXED, __HIP_MEMORY_SCOPE_AGENT);
          wl1 = val1 ? __hip_atomic_load(&src[64 + lane], __ATOMIC_RELAXED, __HIP_MEMORY_SCOPE_AGENT) : 0.f;
        }
      } else {
        wl0 = wbuf[p][j - 1][lane];
        wl1 = val1 ? wbuf[p][j - 1][64 + lane] : 0.f;
      }
      if (hasNext) {
        if (j == 2) {
          if (k == 0) { wn0 = wp0; wn1 = wp1; }
          else {
            if (!dead) {
              long guard = 0;
              while (__hip_atomic_load(&flags[conRIdx], __ATOMIC_ACQUIRE, __HIP_MEMORY_SCOPE_AGENT) < k) {
                __builtin_amdgcn_s_sleep(8);
                if (++guard > (1L << 20)) { dead = true; break; }
              }
            }
            const float* src = pbuf + ((size_t)conRIdx * 2 + (k & 1)) * 100;
            wn0 = __hip_atomic_load(&src[lane], __ATOMIC_RELAXED, __HIP_MEMORY_SCOPE_AGENT);
            wn1 = val1 ? __hip_atomic_load(&src[64 + lane], __ATOMIC_RELAXED, __HIP_MEMORY_SCOPE_AGENT) : 0.f;
          }
        } else {
          wn0 = wbuf[p][j + 1][lane];
          wn1 = val1 ? wbuf[p][j + 1][64 + lane] : 0.f;
        }
      }

      float dw0 = w0 - wl0;
      float g0  = fmaf(cM, mu0, cY * y0) + CC_ * (dw0 * rsqrtf(fmaf(dw0, dw0, 1e-10f)));
      if (hasNext) { float dn0 = wn0 - w0; g0 -= CC_ * (dn0 * rsqrtf(fmaf(dn0, dn0, 1e-10f))); }
      float v0 = fmaf(-LR_, g0, w0);
      float v1 = 0.f;
      if (val1) {
        float dw1 = w1 - wl1;
        float g1  = fmaf(cM, mu1, cY * y1) + CC_ * (dw1 * rsqrtf(fmaf(dw1, dw1, 1e-10f)));
        if (hasNext) { float dn1 = wn1 - w1; g1 -= CC_ * (dn1 * rsqrtf(fmaf(dn1, dn1, 1e-10f))); }
        v1 = fmaf(-LR_, g1, w1);
      }

      // ---- Michelot simplex projection (exact, finite convergence) ----
      float a1m   = val1 ? 1.f : 0.f;
      float Ssum  = wred64(v0 + a1m * v1);
      float Cnt   = wred64(1.f + a1m);
      float theta = 0.f;
      for (int it = 0; it < 100; ++it) {
        theta = (Ssum - 1.f) / Cnt;
        float na0 = (v0 > theta) ? 1.f : 0.f;
        float na1 = (val1 && (v1 > theta)) ? 1.f : 0.f;
        float ns = wred64(na0 * v0 + na1 * v1);
        float nc = wred64(na0 + na1);
        if (nc == Cnt) break;
        Ssum = ns; Cnt = nc;
      }
      w0 = fmaxf(v0 - theta, 0.f);
      w1 = val1 ? fmaxf(v1 - theta, 0.f) : 0.f;

      wbuf[1 - p][j][lane] = w0;
      if (val1) wbuf[1 - p][j][64 + lane] = w1;

      if (pubR || pubL) {
        float* dst = pbuf + ((size_t)pubIdx * 2 + ((k + 1) & 1)) * 100;
        __hip_atomic_store(&dst[lane], w0, __ATOMIC_RELAXED, __HIP_MEMORY_SCOPE_AGENT);
        if (val1) __hip_atomic_store(&dst[64 + lane], w1, __ATOMIC_RELAXED, __HIP_MEMORY_SCOPE_AGENT);
        if (lane == 0)
          __hip_atomic_store(&flags[pubIdx], k + 1, __ATOMIC_RELEASE, __HIP_MEMORY_SCOPE_AGENT);
      }
    }
    __syncthreads();
  }

  if (sub == 0) {
    float* o = out + (size_t)bh * 100;
    o[lane] = w0;
    if (val1) o[64 + lane] = w1;
  }
}

extern "C" void kernel_launch(void* const* d_in, const int* in_sizes, int n_in,
                              void* d_out, int out_size, void* d_ws, size_t ws_size,
                              hipStream_t stream) {
  const float* mu = (const float*)d_in[0];
  const float* L  = (const float*)d_in[1];
  const float* wp = (const float*)d_in[2];
  const float* cl = (const float*)d_in[3];
  float* pbuf  = (float*)d_ws;
  int*   flags = (int*)((char*)d_ws + PBUF_BYTES);
  hipMemsetAsync(flags, 0, FLAG_COUNT * sizeof(int), stream);
  hipLaunchKernelGGL(mpo_solver, dim3(512), dim3(768), 0, stream,
                     mu, L, wp, cl, (float*)d_out, pbuf, flags);
}

// Round 3
// 3114.928 us; speedup vs baseline: 3.0906x; 3.0906x over previous
//
#include <hip/hip_runtime.h>
#include <cstdint>
#include <cstddef>

// Problem constants (match reference)
#define NIT    500
#define GAMMA_ 5.0f
#define CC_    1e-3f
#define KAPPA_ 2.0627128075074256f
#define PEN_   100.0f
#define LR_    0.01f

// d_ws layout: pbuf [128 b][2 dir][2 parity][100] f32 = 204800 B, then flags [256] int
#define PBUF_BYTES 204800
#define FLAG_COUNT 256

__device__ __forceinline__ float wred64(float x) {
#pragma unroll
  for (int m = 1; m < 64; m <<= 1) x += __shfl_xor(x, m, 64);
  return x;
}
__device__ __forceinline__ float rdlane(float v, int lane) {
  return __int_as_float(__builtin_amdgcn_readlane(__float_as_int(v), lane));
}

// One WG per (b, half): 6 heads, 12 waves (2 waves/head). S rows live in VGPRs.
// __launch_bounds__(768, 1): minBlocks=1 -> VGPR cap ~168 (12-wave block launchability).
// Rounds 1/2 proved that larger 2nd args make the backend target impossible occupancy
// and spill S to scratch (VGPR_Count 76/40 == the 2/3-block caps).
__global__ __launch_bounds__(768, 1) void mpo_solver(
    const float* __restrict__ mu, const float* __restrict__ L,
    const float* __restrict__ wprev, const float* __restrict__ climit,
    float* __restrict__ out, float* __restrict__ pbuf, int* __restrict__ flags)
{
  const int tid  = threadIdx.x;
  const int lane = tid & 63;
  const int wave = __builtin_amdgcn_readfirstlane(tid >> 6);  // 0..11
  const int j    = wave >> 1;       // local head 0..5
  const int sec  = wave & 1;        // 0 = rows 0-49 + post, 1 = rows 50-99
  const int bid  = blockIdx.x;
  const int b    = bid & 127;
  const int half = bid >> 7;        // 0: heads 0-5, 1: heads 6-11
  const int h    = half * 6 + j;    // global head
  const int bh   = b * 12 + h;

  __shared__ float wbuf[2][6][100];   // double-buffered w per head
  __shared__ float ybuf[6][100];      // y = S w per head

  const float* Lb = L + (size_t)bh * 10000;

  // ---------- Phase 0: SYRK. Lane owns row r of S = L L^T (fp32, in registers). ----------
  float S[100];
#pragma unroll
  for (int c = 0; c < 100; ++c) S[c] = 0.f;
  const int r = sec * 50 + lane;      // valid row iff lane < 50
  if (lane < 50) {
#pragma unroll 1
    for (int mc = 0; mc < 25; ++mc) {
      float4 lr = *(const float4*)(Lb + r * 100 + mc * 4);
#pragma unroll
      for (int c = 0; c < 100; ++c) {
        const float* Lc = Lb + c * 100 + mc * 4;   // wave-uniform address -> scalar loads
        S[c] = fmaf(lr.x, Lc[0], fmaf(lr.y, Lc[1], fmaf(lr.z, Lc[2], fmaf(lr.w, Lc[3], S[c]))));
      }
    }
  }

  const bool val1 = (lane < 36);
  float mu0 = mu[(size_t)bh * 100 + lane];
  float mu1 = val1 ? mu[(size_t)bh * 100 + 64 + lane] : 0.f;
  float wp0 = wprev[b * 100 + lane];
  float wp1 = val1 ? wprev[b * 100 + 64 + lane] : 0.f;
  float lim = climit[b];

  float w0 = wp0, w1 = wp1;           // post wave's iterate (n = lane, 64+lane)

  if (sec == 0) {
    wbuf[0][j][lane] = wp0;
    if (val1) wbuf[0][j][64 + lane] = wp1;
  }
  __syncthreads();

  const bool hasNext = (h < 11);
  const bool isPubL  = (half == 0) && (j == 5);  // publishes head 5, consumes head 6
  const bool isPubH  = (half == 1) && (j == 0);  // publishes head 6, consumes head 5
  const int  flagPub = isPubL ? (b * 2 + 0) : (b * 2 + 1);
  const int  flagCon = isPubL ? (b * 2 + 1) : (b * 2 + 0);  // what this boundary wave consumes
  const bool isCon   = (sec == 0) && (isPubL || isPubH);
  bool dead = false;

  for (int k = 0; k < NIT; ++k) {
    const int p = k & 1;

    // ---------- boundary prefetch (overlap partner-load latency with matvec) ----------
    float pf0 = 0.f, pf1 = 0.f;
    bool pfReady = false;
    if (isCon && k > 0) {
      if (__hip_atomic_load(&flags[flagCon], __ATOMIC_ACQUIRE, __HIP_MEMORY_SCOPE_AGENT) >= k) {
        const float* src = pbuf + ((size_t)flagCon * 2 + (k & 1)) * 100;
        pf0 = __hip_atomic_load(&src[lane], __ATOMIC_RELAXED, __HIP_MEMORY_SCOPE_AGENT);
        pf1 = val1 ? __hip_atomic_load(&src[64 + lane], __ATOMIC_RELAXED, __HIP_MEMORY_SCOPE_AGENT) : 0.f;
        pfReady = true;
      }
    }

    // ---------- matvec y = S * w_k (all 12 waves, 4 accumulators) ----------
    float vw0 = wbuf[p][j][lane];
    float vw1 = val1 ? wbuf[p][j][64 + lane] : 0.f;
    {
      float a0 = 0.f, a1 = 0.f, a2 = 0.f, a3 = 0.f;
#pragma unroll
      for (int c = 0; c < 64; c += 4) {
        a0 = fmaf(rdlane(vw0, c + 0), S[c + 0], a0);
        a1 = fmaf(rdlane(vw0, c + 1), S[c + 1], a1);
        a2 = fmaf(rdlane(vw0, c + 2), S[c + 2], a2);
        a3 = fmaf(rdlane(vw0, c + 3), S[c + 3], a3);
      }
#pragma unroll
      for (int c = 64; c < 100; c += 4) {
        a0 = fmaf(rdlane(vw1, c - 64), S[c + 0], a0);
        a1 = fmaf(rdlane(vw1, c - 63), S[c + 1], a1);
        a2 = fmaf(rdlane(vw1, c - 62), S[c + 2], a2);
        a3 = fmaf(rdlane(vw1, c - 61), S[c + 3], a3);
      }
      if (lane < 50) ybuf[j][r] = (a0 + a2) + (a1 + a3);
    }
    __syncthreads();

    // ---------- post phase: primary wave per head ----------
    if (sec == 0) {
      float y0 = ybuf[j][lane];
      float y1 = val1 ? ybuf[j][64 + lane] : 0.f;

      float ret = wred64(fmaf(mu0, w0, mu1 * w1));
      float s2  = wred64(fmaf(y0, w0, y1 * w1));
      float sigma = sqrtf(s2 + 1e-12f);
      float z     = KAPPA_ * sigma - ret - lim;
      float act   = (z > 0.f) ? 1.f : 0.f;
      float cY    = 2.f * GAMMA_ + act * (PEN_ * KAPPA_ / sigma);
      float cM    = -(1.f + act * PEN_);

      // neighbor w (current iterate k, Jacobi)
      float wl0, wl1, wn0 = 0.f, wn1 = 0.f;
      if (j == 0) {
        if (half == 0 || k == 0) { wl0 = wp0; wl1 = wp1; }
        else {
          if (!pfReady) {
            if (!dead) {
              long guard = 0;
              while (__hip_atomic_load(&flags[flagCon], __ATOMIC_ACQUIRE, __HIP_MEMORY_SCOPE_AGENT) < k) {
                __builtin_amdgcn_s_sleep(8);
                if (++guard > (1L << 20)) { dead = true; break; }
              }
            }
            const float* src = pbuf + ((size_t)flagCon * 2 + (k & 1)) * 100;
            pf0 = __hip_atomic_load(&src[lane], __ATOMIC_RELAXED, __HIP_MEMORY_SCOPE_AGENT);
            pf1 = val1 ? __hip_atomic_load(&src[64 + lane], __ATOMIC_RELAXED, __HIP_MEMORY_SCOPE_AGENT) : 0.f;
          }
          wl0 = pf0; wl1 = pf1;
        }
      } else { wl0 = wbuf[p][j - 1][lane]; wl1 = val1 ? wbuf[p][j - 1][64 + lane] : 0.f; }
      if (hasNext) {
        if (j == 5) {  // half==0 boundary: next is head 6
          if (k == 0) { wn0 = wp0; wn1 = wp1; }
          else {
            if (!pfReady) {
              if (!dead) {
                long guard = 0;
                while (__hip_atomic_load(&flags[flagCon], __ATOMIC_ACQUIRE, __HIP_MEMORY_SCOPE_AGENT) < k) {
                  __builtin_amdgcn_s_sleep(8);
                  if (++guard > (1L << 20)) { dead = true; break; }
                }
              }
              const float* src = pbuf + ((size_t)flagCon * 2 + (k & 1)) * 100;
              pf0 = __hip_atomic_load(&src[lane], __ATOMIC_RELAXED, __HIP_MEMORY_SCOPE_AGENT);
              pf1 = val1 ? __hip_atomic_load(&src[64 + lane], __ATOMIC_RELAXED, __HIP_MEMORY_SCOPE_AGENT) : 0.f;
            }
            wn0 = pf0; wn1 = pf1;
          }
        } else { wn0 = wbuf[p][j + 1][lane]; wn1 = val1 ? wbuf[p][j + 1][64 + lane] : 0.f; }
      }

      float dw0 = w0 - wl0;
      float g0  = fmaf(cM, mu0, cY * y0) + CC_ * (dw0 * rsqrtf(fmaf(dw0, dw0, 1e-10f)));
      if (hasNext) { float dn0 = wn0 - w0; g0 -= CC_ * (dn0 * rsqrtf(fmaf(dn0, dn0, 1e-10f))); }
      float v0 = fmaf(-LR_, g0, w0);
      float v1 = 0.f;
      if (val1) {
        float dw1 = w1 - wl1;
        float g1  = fmaf(cM, mu1, cY * y1) + CC_ * (dw1 * rsqrtf(fmaf(dw1, dw1, 1e-10f)));
        if (hasNext) { float dn1 = wn1 - w1; g1 -= CC_ * (dn1 * rsqrtf(fmaf(dn1, dn1, 1e-10f))); }
        v1 = fmaf(-LR_, g1, w1);
      }

      // ---- Michelot simplex projection (exact, finite convergence) ----
      float a1m   = val1 ? 1.f : 0.f;
      float Ssum  = wred64(v0 + a1m * v1);
      float Cnt   = wred64(1.f + a1m);
      float theta = 0.f;
      for (int it = 0; it < 100; ++it) {
        theta = (Ssum - 1.f) / Cnt;
        float na0 = (v0 > theta) ? 1.f : 0.f;
        float na1 = (val1 && (v1 > theta)) ? 1.f : 0.f;
        float ns = wred64(na0 * v0 + na1 * v1);
        float nc = wred64(na0 + na1);
        if (nc == Cnt) break;
        Ssum = ns; Cnt = nc;
      }
      w0 = fmaxf(v0 - theta, 0.f);
      w1 = val1 ? fmaxf(v1 - theta, 0.f) : 0.f;

      wbuf[1 - p][j][lane] = w0;
      if (val1) wbuf[1 - p][j][64 + lane] = w1;

      if (isPubL || isPubH) {
        float* dst = pbuf + ((size_t)flagPub * 2 + ((k + 1) & 1)) * 100;
        __hip_atomic_store(&dst[lane], w0, __ATOMIC_RELAXED, __HIP_MEMORY_SCOPE_AGENT);
        if (val1) __hip_atomic_store(&dst[64 + lane], w1, __ATOMIC_RELAXED, __HIP_MEMORY_SCOPE_AGENT);
        if (lane == 0)
          __hip_atomic_store(&flags[flagPub], k + 1, __ATOMIC_RELEASE, __HIP_MEMORY_SCOPE_AGENT);
      }
    }
    __syncthreads();
  }

  if (sec == 0) {
    float* o = out + (size_t)bh * 100;
    o[lane] = w0;
    if (val1) o[64 + lane] = w1;
  }
}

extern "C" void kernel_launch(void* const* d_in, const int* in_sizes, int n_in,
                              void* d_out, int out_size, void* d_ws, size_t ws_size,
                              hipStream_t stream) {
  const float* mu = (const float*)d_in[0];
  const float* L  = (const float*)d_in[1];
  const float* wp = (const float*)d_in[2];
  const float* cl = (const float*)d_in[3];
  float* pbuf  = (float*)d_ws;
  int*   flags = (int*)((char*)d_ws + PBUF_BYTES);
  hipMemsetAsync(flags, 0, FLAG_COUNT * sizeof(int), stream);
  hipLaunchKernelGGL(mpo_solver, dim3(256), dim3(768), 0, stream,
                     mu, L, wp, cl, (float*)d_out, pbuf, flags);
}

// Round 5
// 3018.742 us; speedup vs baseline: 3.1891x; 1.0319x over previous
//
#include <hip/hip_runtime.h>
#include <cstdint>
#include <cstddef>

// Problem constants (match reference)
#define NIT    500
#define GAMMA_ 5.0f
#define CC_    1e-3f
#define KAPPA_ 2.0627128075074256f
#define PEN_   100.0f
#define LR_    0.01f

// d_ws layout: pbuf [128 b][2 dir][4 slot][100] f32 = 409600 B, then flags [256] int
#define PBUF_BYTES (128*2*4*100*4)
#define FLAG_COUNT 256

__device__ __forceinline__ float rdlane(float v, int lane) {
  return __int_as_float(__builtin_amdgcn_readlane(__float_as_int(v), lane));
}

// Wave64 sum via DPP (row_shr 1,2,4,8 ; row_bcast15 -> rows1,3 ; row_bcast31 -> rows2,3).
// Total lands in lane 63; broadcast with readlane. ~13 VALU ops, ~60 cyc latency
// vs ~200 cyc for the ds_swizzle shfl_xor ladder. Verified numerics in round 4
// (its 1.9e-2 failure was the stale-neighbor protocol, magnitude-matched to the
// smoothed-sign drift; a broken reduction would give O(0.1+) error).
__device__ __forceinline__ float wred64(float x) {
  int t;
  t = __builtin_amdgcn_update_dpp(0, __float_as_int(x), 0x111, 0xf, 0xf, true); x += __int_as_float(t);
  t = __builtin_amdgcn_update_dpp(0, __float_as_int(x), 0x112, 0xf, 0xf, true); x += __int_as_float(t);
  t = __builtin_amdgcn_update_dpp(0, __float_as_int(x), 0x114, 0xf, 0xf, true); x += __int_as_float(t);
  t = __builtin_amdgcn_update_dpp(0, __float_as_int(x), 0x118, 0xf, 0xf, true); x += __int_as_float(t);
  t = __builtin_amdgcn_update_dpp(0, __float_as_int(x), 0x142, 0xa, 0xf, true); x += __int_as_float(t);
  t = __builtin_amdgcn_update_dpp(0, __float_as_int(x), 0x143, 0xc, 0xf, true); x += __int_as_float(t);
  return rdlane(x, 63);
}

// One WG per (b, half): 6 heads, 12 waves (2 waves/head). S rows live in VGPR/AGPR.
// Boundary 5<->6 exchanged cross-WG with EXACT iterate-k handshake (stale neighbors
// provably drift through the smoothed-sign turnover term — round 4).
__global__ __launch_bounds__(768, 1) void mpo_solver(
    const float* __restrict__ mu, const float* __restrict__ L,
    const float* __restrict__ wprev, const float* __restrict__ climit,
    float* __restrict__ out, float* __restrict__ pbuf, int* __restrict__ flags)
{
  const int tid  = threadIdx.x;
  const int lane = tid & 63;
  const int wave = __builtin_amdgcn_readfirstlane(tid >> 6);  // 0..11
  const int j    = wave >> 1;       // local head 0..5
  const int sec  = wave & 1;        // 0 = rows 0-49 + post, 1 = rows 50-99
  const int bid  = blockIdx.x;
  const int b    = bid & 127;
  const int half = bid >> 7;        // 0: heads 0-5, 1: heads 6-11
  const int h    = half * 6 + j;    // global head
  const int bh   = b * 12 + h;

  __shared__ float wbuf[2][6][100];   // double-buffered w per head
  __shared__ float ybuf[6][100];      // y = S w per head

  const float* Lb = L + (size_t)bh * 10000;

  // ---------- Phase 0: SYRK. Lane owns row r of S = L L^T (fp32, in registers). ----------
  float S[100];
#pragma unroll
  for (int c = 0; c < 100; ++c) S[c] = 0.f;
  const int r = sec * 50 + lane;      // valid row iff lane < 50
  if (lane < 50) {
#pragma unroll 1
    for (int mc = 0; mc < 25; ++mc) {
      float4 lr = *(const float4*)(Lb + r * 100 + mc * 4);
#pragma unroll
      for (int c = 0; c < 100; ++c) {
        const float* Lc = Lb + c * 100 + mc * 4;   // wave-uniform address -> scalar loads
        S[c] = fmaf(lr.x, Lc[0], fmaf(lr.y, Lc[1], fmaf(lr.z, Lc[2], fmaf(lr.w, Lc[3], S[c]))));
      }
    }
  }

  const bool val1 = (lane < 36);
  float mu0 = mu[(size_t)bh * 100 + lane];
  float mu1 = val1 ? mu[(size_t)bh * 100 + 64 + lane] : 0.f;
  float wp0 = wprev[b * 100 + lane];
  float wp1 = val1 ? wprev[b * 100 + 64 + lane] : 0.f;
  float lim = climit[b];

  float w0 = wp0, w1 = wp1;           // post wave's iterate (n = lane, 64+lane)

  if (sec == 0) {
    wbuf[0][j][lane] = wp0;
    if (val1) wbuf[0][j][64 + lane] = wp1;
  }
  __syncthreads();

  const bool hasNext = (h < 11);
  const bool isPubL  = (half == 0) && (j == 5);  // publishes head 5, consumes head 6
  const bool isPubH  = (half == 1) && (j == 0);  // publishes head 6, consumes head 5
  const int  flagPub = isPubL ? (b * 2 + 0) : (b * 2 + 1);
  const int  flagCon = isPubL ? (b * 2 + 1) : (b * 2 + 0);
  const bool isCon   = (sec == 0) && (isPubL || isPubH);
  bool dead = false;

  for (int k = 0; k < NIT; ++k) {
    const int p = k & 1;

    // ---------- matvec y = S * w_k (all 12 waves, 4 accumulators) ----------
    float vw0 = wbuf[p][j][lane];
    float vw1 = val1 ? wbuf[p][j][64 + lane] : 0.f;
    {
      float a0 = 0.f, a1 = 0.f, a2 = 0.f, a3 = 0.f;
#pragma unroll
      for (int c = 0; c < 64; c += 4) {
        a0 = fmaf(rdlane(vw0, c + 0), S[c + 0], a0);
        a1 = fmaf(rdlane(vw0, c + 1), S[c + 1], a1);
        a2 = fmaf(rdlane(vw0, c + 2), S[c + 2], a2);
        a3 = fmaf(rdlane(vw0, c + 3), S[c + 3], a3);
      }
#pragma unroll
      for (int c = 64; c < 100; c += 4) {
        a0 = fmaf(rdlane(vw1, c - 64), S[c + 0], a0);
        a1 = fmaf(rdlane(vw1, c - 63), S[c + 1], a1);
        a2 = fmaf(rdlane(vw1, c - 62), S[c + 2], a2);
        a3 = fmaf(rdlane(vw1, c - 61), S[c + 3], a3);
      }
      if (lane < 50) ybuf[j][r] = (a0 + a2) + (a1 + a3);
    }

    // ---------- boundary prefetch AFTER matvec: partner published w(k) at the end
    // of its post(k-1), i.e. one full matvec-phase ago in lockstep -> usually ready.
    float pf0 = 0.f, pf1 = 0.f;
    bool pfReady = false;
    if (isCon && k > 0) {
      if (__hip_atomic_load(&flags[flagCon], __ATOMIC_ACQUIRE, __HIP_MEMORY_SCOPE_AGENT) >= k) {
        const float* src = pbuf + ((size_t)flagCon * 4 + (k & 3)) * 100;
        pf0 = __hip_atomic_load(&src[lane], __ATOMIC_RELAXED, __HIP_MEMORY_SCOPE_AGENT);
        pf1 = val1 ? __hip_atomic_load(&src[64 + lane], __ATOMIC_RELAXED, __HIP_MEMORY_SCOPE_AGENT) : 0.f;
        pfReady = true;
      }
    }
    __syncthreads();

    // ---------- post phase: primary wave per head ----------
    if (sec == 0) {
      float y0 = ybuf[j][lane];
      float y1 = val1 ? ybuf[j][64 + lane] : 0.f;

      // ret and s2 reductions are independent -> their DPP chains interleave (ILP)
      float ret = wred64(fmaf(mu0, w0, mu1 * w1));
      float s2  = wred64(fmaf(y0, w0, y1 * w1));
      float sigma = sqrtf(s2 + 1e-12f);
      float z     = KAPPA_ * sigma - ret - lim;
      float act   = (z > 0.f) ? 1.f : 0.f;
      float cY    = 2.f * GAMMA_ + act * (PEN_ * KAPPA_ / sigma);
      float cM    = -(1.f + act * PEN_);

      // neighbor w (iterate k exactly — Jacobi, matches reference)
      float wl0, wl1, wn0 = 0.f, wn1 = 0.f;
      if (j == 0) {
        if (half == 0 || k == 0) { wl0 = wp0; wl1 = wp1; }
        else {
          if (!pfReady) {
            if (!dead) {
              long guard = 0;
              while (__hip_atomic_load(&flags[flagCon], __ATOMIC_ACQUIRE, __HIP_MEMORY_SCOPE_AGENT) < k) {
                __builtin_amdgcn_s_sleep(8);
                if (++guard > (1L << 20)) { dead = true; break; }
              }
            }
            const float* src = pbuf + ((size_t)flagCon * 4 + (k & 3)) * 100;
            pf0 = __hip_atomic_load(&src[lane], __ATOMIC_RELAXED, __HIP_MEMORY_SCOPE_AGENT);
            pf1 = val1 ? __hip_atomic_load(&src[64 + lane], __ATOMIC_RELAXED, __HIP_MEMORY_SCOPE_AGENT) : 0.f;
          }
          wl0 = pf0; wl1 = pf1;
        }
      } else { wl0 = wbuf[p][j - 1][lane]; wl1 = val1 ? wbuf[p][j - 1][64 + lane] : 0.f; }
      if (hasNext) {
        if (j == 5) {  // half==0 boundary: next is head 6
          if (k == 0) { wn0 = wp0; wn1 = wp1; }
          else {
            if (!pfReady) {
              if (!dead) {
                long guard = 0;
                while (__hip_atomic_load(&flags[flagCon], __ATOMIC_ACQUIRE, __HIP_MEMORY_SCOPE_AGENT) < k) {
                  __builtin_amdgcn_s_sleep(8);
                  if (++guard > (1L << 20)) { dead = true; break; }
                }
              }
              const float* src = pbuf + ((size_t)flagCon * 4 + (k & 3)) * 100;
              pf0 = __hip_atomic_load(&src[lane], __ATOMIC_RELAXED, __HIP_MEMORY_SCOPE_AGENT);
              pf1 = val1 ? __hip_atomic_load(&src[64 + lane], __ATOMIC_RELAXED, __HIP_MEMORY_SCOPE_AGENT) : 0.f;
            }
            wn0 = pf0; wn1 = pf1;
          }
        } else { wn0 = wbuf[p][j + 1][lane]; wn1 = val1 ? wbuf[p][j + 1][64 + lane] : 0.f; }
      }

      float dw0 = w0 - wl0;
      float g0  = fmaf(cM, mu0, cY * y0) + CC_ * (dw0 * rsqrtf(fmaf(dw0, dw0, 1e-10f)));
      if (hasNext) { float dn0 = wn0 - w0; g0 -= CC_ * (dn0 * rsqrtf(fmaf(dn0, dn0, 1e-10f))); }
      float v0 = fmaf(-LR_, g0, w0);
      float v1 = 0.f;
      if (val1) {
        float dw1 = w1 - wl1;
        float g1  = fmaf(cM, mu1, cY * y1) + CC_ * (dw1 * rsqrtf(fmaf(dw1, dw1, 1e-10f)));
        if (hasNext) { float dn1 = wn1 - w1; g1 -= CC_ * (dn1 * rsqrtf(fmaf(dn1, dn1, 1e-10f))); }
        v1 = fmaf(-LR_, g1, w1);
      }

      // ---- Michelot simplex projection (exact, finite convergence) ----
      float a1m   = val1 ? 1.f : 0.f;
      float Ssum  = wred64(v0 + a1m * v1);
      float Cnt   = wred64(1.f + a1m);
      float theta = 0.f;
      for (int it = 0; it < 100; ++it) {
        theta = (Ssum - 1.f) / Cnt;
        float na0 = (v0 > theta) ? 1.f : 0.f;
        float na1 = (val1 && (v1 > theta)) ? 1.f : 0.f;
        // ns and nc are independent -> interleaved DPP chains
        float ns = wred64(na0 * v0 + na1 * v1);
        float nc = wred64(na0 + na1);
        if (nc == Cnt) break;
        Ssum = ns; Cnt = nc;
      }
      w0 = fmaxf(v0 - theta, 0.f);
      w1 = val1 ? fmaxf(v1 - theta, 0.f) : 0.f;

      wbuf[1 - p][j][lane] = w0;
      if (val1) wbuf[1 - p][j][64 + lane] = w1;

      if (isPubL || isPubH) {
        float* dst = pbuf + ((size_t)flagPub * 4 + ((k + 1) & 3)) * 100;
        __hip_atomic_store(&dst[lane], w0, __ATOMIC_RELAXED, __HIP_MEMORY_SCOPE_AGENT);
        if (val1) __hip_atomic_store(&dst[64 + lane], w1, __ATOMIC_RELAXED, __HIP_MEMORY_SCOPE_AGENT);
        if (lane == 0)
          __hip_atomic_store(&flags[flagPub], k + 1, __ATOMIC_RELEASE, __HIP_MEMORY_SCOPE_AGENT);
      }
    }
    __syncthreads();
  }

  if (sec == 0) {
    float* o = out + (size_t)bh * 100;
    o[lane] = w0;
    if (val1) o[64 + lane] = w1;
  }
}

extern "C" void kernel_launch(void* const* d_in, const int* in_sizes, int n_in,
                              void* d_out, int out_size, void* d_ws, size_t ws_size,
                              hipStream_t stream) {
  const float* mu = (const float*)d_in[0];
  const float* L  = (const float*)d_in[1];
  const float* wp = (const float*)d_in[2];
  const float* cl = (const float*)d_in[3];
  float* pbuf  = (float*)d_ws;
  int*   flags = (int*)((char*)d_ws + PBUF_BYTES);
  hipMemsetAsync(flags, 0, FLAG_COUNT * sizeof(int), stream);
  hipLaunchKernelGGL(mpo_solver, dim3(256), dim3(768), 0, stream,
                     mu, L, wp, cl, (float*)d_out, pbuf, flags);
}